// Round 7
// baseline (84.608 us; speedup 1.0000x reference)
//
#include <hip/hip_runtime.h>

// YOLO loss: N=4096, S=14, B=2, NC=20. ncells = 802816 = 1568 blocks * 512.
// R7 = R6 (34.9 us) + conditional pred loads (noobj thread-pairs issue 4
// f4 txns instead of 15 -- L1 transaction amplification is the theory'd
// ~10us pool; line traffic unchanged) + fused last-block finalize with
// plain-store slots (memset shrinks to 4B counter, finalize launch gone).

#define GS 14
#define NCLS 20
#define BLOCK 256
#define CPT 2
#define CPB (BLOCK * CPT)   // 512 cells per block

// ws layout:
//   ((int*)ws)[0]      : block arrival counter (memset to 0 each call)
//   ws[16 + b*4 + k]   : block b's partials {reg, cont, noobj, cls} (plain stores)
#define WS_SLOT0 16

template <int CB>
__device__ __forceinline__ void cell_compute(const float (&v)[60],
                                             const float4 tb4,
                                             const float* __restrict__ tcls,
                                             int cell, bool m,
                                             float& reg, float& cont,
                                             float& noobj, float& cls) {
    const float invS = 1.0f / (float)GS;
    if (m) {
        const float tx = tb4.x, ty = tb4.y, tw = tb4.z, th = tb4.w;

        const float tcx = tx * invS, tcy = ty * invS;
        const float t_x1 = tcx - 0.5f * tw, t_y1 = tcy - 0.5f * th;
        const float t_x2 = tcx + 0.5f * tw, t_y2 = tcy + 0.5f * th;
        const float ta = (t_x2 - t_x1) * (t_y2 - t_y1);

        const float b0x = v[CB + 0], b0y = v[CB + 1], b0w = v[CB + 2], b0h = v[CB + 3], b0c = v[CB + 4];
        const float b1x = v[CB + 5], b1y = v[CB + 6], b1w = v[CB + 7], b1h = v[CB + 8], b1c = v[CB + 9];

        float iou0, iou1;
        {
            const float cx = b0x * invS, cy = b0y * invS;
            const float x1 = cx - 0.5f * b0w, y1 = cy - 0.5f * b0h;
            const float x2 = cx + 0.5f * b0w, y2 = cy + 0.5f * b0h;
            const float iw = fmaxf(fminf(x2, t_x2) - fmaxf(x1, t_x1), 0.0f);
            const float ih = fmaxf(fminf(y2, t_y2) - fmaxf(y1, t_y1), 0.0f);
            const float inter = iw * ih;
            const float pa = (x2 - x1) * (y2 - y1);
            iou0 = inter / (pa + ta - inter);
        }
        {
            const float cx = b1x * invS, cy = b1y * invS;
            const float x1 = cx - 0.5f * b1w, y1 = cy - 0.5f * b1h;
            const float x2 = cx + 0.5f * b1w, y2 = cy + 0.5f * b1h;
            const float iw = fmaxf(fminf(x2, t_x2) - fmaxf(x1, t_x1), 0.0f);
            const float ih = fmaxf(fminf(y2, t_y2) - fmaxf(y1, t_y1), 0.0f);
            const float inter = iw * ih;
            const float pa = (x2 - x1) * (y2 - y1);
            iou1 = inter / (pa + ta - inter);
        }

        const bool sel1 = iou1 > iou0;   // jnp.argmax: first max wins -> strict >
        const float biou = fmaxf(iou0, iou1);
        const float rx = sel1 ? b1x : b0x;
        const float ry = sel1 ? b1y : b0y;
        const float rw = sel1 ? b1w : b0w;
        const float rh = sel1 ? b1h : b0h;
        const float rc = sel1 ? b1c : b0c;

        const float d0 = rx - tx, d1 = ry - ty;
        const float d2 = sqrtf(rw) - sqrtf(tw);
        const float d3 = sqrtf(rh) - sqrtf(th);
        reg += d0 * d0 + d1 * d1 + d2 * d2 + d3 * d3;

        const float dc = rc - biou;
        cont += dc * dc;

        const float4* tc4 = reinterpret_cast<const float4*>(tcls + (size_t)cell * NCLS);
        float csum = 0.0f;
        #pragma unroll
        for (int j = 0; j < 5; ++j) {
            const float4 t4 = tc4[j];
            float d;
            d = v[CB + 10 + j * 4 + 0] - t4.x; csum += d * d;
            d = v[CB + 10 + j * 4 + 1] - t4.y; csum += d * d;
            d = v[CB + 10 + j * 4 + 2] - t4.z; csum += d * d;
            d = v[CB + 10 + j * 4 + 3] - t4.w; csum += d * d;
        }
        cls += csum;
    } else {
        const float c0 = v[CB + 4], c1 = v[CB + 9];
        noobj += c0 * c0 + c1 * c1;
    }
}

__launch_bounds__(BLOCK)
__global__ void yolo_loss_kernel(const float* __restrict__ pred,
                                 const float* __restrict__ tbox,
                                 const float* __restrict__ tcls,
                                 const void* __restrict__ mask,
                                 float* __restrict__ ws,
                                 int ncells, float inv_n,
                                 float* __restrict__ out) {
    const int tid = threadIdx.x;

    // ---- per-block mask-dtype sniff on the first 4KB (one barrier) ----
    //   fmt=0: int32, fmt=1: uint8/bool, fmt=2: float32
    int my_bits = 0;
    if (ncells >= 4096) {
        const uint4 w4 = reinterpret_cast<const uint4*>(mask)[tid];  // bytes 16t..16t+15
        const unsigned a = w4.x | w4.y | w4.z | w4.w;
        my_bits  = ((a & 0xFEFEFEFEu) != 0) ? 2 : 0;   // any byte with bits above bit0 -> float
        my_bits |= ((a & 0xFFFFFF00u) != 0) ? 1 : 0;   // nonzero byte at off%4 != 0 -> u8
    } else if (tid == 0) {
        const unsigned char* mb = (const unsigned char*)mask;
        for (int i = 0; i < ncells; ++i) {
            if (mb[i] > 1) my_bits |= 2;
            if ((i & 3) != 0 && mb[i] != 0) my_bits |= 1;
        }
    }
    const int bits = __syncthreads_or(my_bits);
    const int fmt = (bits & 2) ? 2 : ((bits & 1) ? 1 : 0);

    const int g = blockIdx.x * BLOCK + tid;
    const int c0 = g * CPT;

    float reg = 0.0f, cont = 0.0f, noobj = 0.0f, cls = 0.0f;

    if (c0 + CPT <= ncells) {
        float v[60];
        float4* v4 = reinterpret_cast<float4*>(v);
        const float4* prow = reinterpret_cast<const float4*>(pred) + (size_t)g * 15;

        // ---- unconditional issue: conf-bearing f4s + mask + tbox ----
        v4[1] = prow[1];   // floats 4..7   (cell0 conf at v[4])
        v4[2] = prow[2];   // floats 8..11  (cell0 box1 conf at v[9])
        v4[8] = prow[8];   // floats 32..35 (cell1 conf at v[34])
        v4[9] = prow[9];   // floats 36..39 (cell1 box1 conf at v[39])

        bool m0, m1;
        if (fmt == 2) {
            const float2 mm = reinterpret_cast<const float2*>(mask)[g];
            m0 = mm.x != 0.0f; m1 = mm.y != 0.0f;
        } else if (fmt == 1) {
            const uchar2 mm = reinterpret_cast<const uchar2*>(mask)[g];
            m0 = mm.x != 0; m1 = mm.y != 0;
        } else {
            const int2 mm = reinterpret_cast<const int2*>(mask)[g];
            m0 = mm.x != 0; m1 = mm.y != 0;
        }

        const float4 tb0 = reinterpret_cast<const float4*>(tbox)[c0];
        const float4 tb1 = reinterpret_cast<const float4*>(tbox)[c0 + 1];

        // ---- remaining 11 f4s only if some cell has an object (28% of threads) ----
        if (m0 | m1) {
            v4[0] = prow[0];
            v4[3] = prow[3]; v4[4] = prow[4]; v4[5] = prow[5];
            v4[6] = prow[6]; v4[7] = prow[7];
            v4[10] = prow[10]; v4[11] = prow[11]; v4[12] = prow[12];
            v4[13] = prow[13]; v4[14] = prow[14];
        }

        cell_compute<0>(v, tb0, tcls, c0,     m0, reg, cont, noobj, cls);
        cell_compute<30>(v, tb1, tcls, c0 + 1, m1, reg, cont, noobj, cls);
    } else if (c0 < ncells) {
        // scalar tail (not hit when ncells % 512 == 0)
        for (int cell = c0; cell < ncells; ++cell) {
            bool m;
            if (fmt == 2)      m = ((const float*)mask)[cell] != 0.0f;
            else if (fmt == 1) m = ((const unsigned char*)mask)[cell] != 0;
            else               m = ((const int*)mask)[cell] != 0;
            float v[60];
            #pragma unroll
            for (int f = 0; f < 30; ++f) v[f] = pred[(size_t)cell * 30 + f];
            float4 tb;
            tb.x = tbox[(size_t)cell * 4 + 0];
            tb.y = tbox[(size_t)cell * 4 + 1];
            tb.z = tbox[(size_t)cell * 4 + 2];
            tb.w = tbox[(size_t)cell * 4 + 3];
            cell_compute<0>(v, tb, tcls, cell, m, reg, cont, noobj, cls);
        }
    }

    // ---- wave64 + block reduce ----
    #pragma unroll
    for (int off = 32; off > 0; off >>= 1) {
        reg   += __shfl_down(reg, off);
        cont  += __shfl_down(cont, off);
        noobj += __shfl_down(noobj, off);
        cls   += __shfl_down(cls, off);
    }

    __shared__ float sred[4][4];
    __shared__ int s_last;
    const int wave = tid >> 6;
    if ((tid & 63) == 0) {
        sred[wave][0] = reg; sred[wave][1] = cont;
        sred[wave][2] = noobj; sred[wave][3] = cls;
    }
    __syncthreads();

    if (tid == 0) {
        float r = 0, c = 0, no = 0, cl = 0;
        #pragma unroll
        for (int w = 0; w < 4; ++w) {
            r += sred[w][0]; c += sred[w][1]; no += sred[w][2]; cl += sred[w][3];
        }
        // plain store (no zeroing needed): every block writes before last reads
        reinterpret_cast<float4*>(ws + WS_SLOT0)[blockIdx.x] = make_float4(r, c, no, cl);
        __threadfence();
        const int prev = atomicAdd((int*)ws, 1);
        s_last = (prev == (int)gridDim.x - 1);
    }
    __syncthreads();

    // ---- last block folds all per-block partials and writes the output ----
    if (s_last) {
        __threadfence();
        float r = 0, c = 0, no = 0, cl = 0;
        for (int b = tid; b < (int)gridDim.x; b += BLOCK) {
            const float4 p = reinterpret_cast<const float4*>(ws + WS_SLOT0)[b];
            r += p.x; c += p.y; no += p.z; cl += p.w;
        }
        #pragma unroll
        for (int off = 32; off > 0; off >>= 1) {
            r  += __shfl_down(r, off);
            c  += __shfl_down(c, off);
            no += __shfl_down(no, off);
            cl += __shfl_down(cl, off);
        }
        if ((tid & 63) == 0) {
            sred[wave][0] = r; sred[wave][1] = c;
            sred[wave][2] = no; sred[wave][3] = cl;
        }
        __syncthreads();
        if (tid == 0) {
            float R = 0, C = 0, NO = 0, CL = 0;
            #pragma unroll
            for (int w = 0; w < 4; ++w) {
                R += sred[w][0]; C += sred[w][1]; NO += sred[w][2]; CL += sred[w][3];
            }
            out[0] = (5.0f * R + 0.5f * NO + C + CL) * inv_n;
            out[1] = R;
            out[2] = C;
            out[3] = NO;
            out[4] = CL;
        }
    }
}

extern "C" void kernel_launch(void* const* d_in, const int* in_sizes, int n_in,
                              void* d_out, int out_size, void* d_ws, size_t ws_size,
                              hipStream_t stream) {
    const float* pred = (const float*)d_in[0];
    const float* tbox = (const float*)d_in[1];
    const float* tcls = (const float*)d_in[2];
    const void*  mask = d_in[3];
    float* ws  = (float*)d_ws;
    float* out = (float*)d_out;

    const int ncells = in_sizes[3];                 // N * S * S
    const int n_img  = ncells / (GS * GS);          // N
    const float inv_n = 1.0f / (float)n_img;

    hipMemsetAsync(ws, 0, sizeof(int), stream);     // arrival counter only

    const int grid = (ncells + CPB - 1) / CPB;      // 1568
    yolo_loss_kernel<<<grid, BLOCK, 0, stream>>>(pred, tbox, tcls, mask, ws,
                                                 ncells, inv_n, out);
}

// Round 8
// 50.124 us; speedup vs baseline: 1.6880x; 1.6880x over previous
//
#include <hip/hip_runtime.h>

// YOLO loss: N=4096, S=14, B=2, NC=20. ncells = 802816.
// R8: algebraic split. noobj = SUM_all(conf^2) - SUM_obj(conf^2).
//  - sweep role (even blocks): coalesced flat-f4 streaming reduction over
//    pred for SUM_all conf^2 -- kills the 8x L1 txn amplification for the
//    85% noobj traffic, with ZERO mask dependence (R7's mistake).
//  - obj role (odd blocks): mask -> gather full rows only for obj cells
//    (15%), computes reg/cont/cls and SUBTRACTS obj conf^2.
// Keeps R6's proven skeleton: per-block dtype sniff, 64-slot spread atomics,
// separate 64-thread finalize, 4KB memset.

#define GS 14
#define NCLS 20
#define BLOCK 256
#define CPT 2
#define CPB (BLOCK * CPT)   // 512 cells per obj block
#define NSLOTS 64
#define SLOT_STRIDE 16      // floats = 64 B

// ws layout (floats): slots at ws[s*16 + k], s in [0,64), k in [0,4)
// k: 0=reg, 1=cont, 2=noobj, 3=cls. Zeroed by hipMemsetAsync each call.

// Obj-cell compute. NEW semantics: noobj accumulates the NEGATIVE of this
// cell's conf^2 when m (sweep already counted it); noobj cells contribute 0.
template <int CB>
__device__ __forceinline__ void cell_compute(const float (&v)[60],
                                             const float* __restrict__ tbox,
                                             const float* __restrict__ tcls,
                                             int cell, bool m,
                                             float& reg, float& cont,
                                             float& noobj, float& cls) {
    const float invS = 1.0f / (float)GS;
    if (m) {
        const float4 tb4 = reinterpret_cast<const float4*>(tbox)[cell];
        const float tx = tb4.x, ty = tb4.y, tw = tb4.z, th = tb4.w;

        const float tcx = tx * invS, tcy = ty * invS;
        const float t_x1 = tcx - 0.5f * tw, t_y1 = tcy - 0.5f * th;
        const float t_x2 = tcx + 0.5f * tw, t_y2 = tcy + 0.5f * th;
        const float ta = (t_x2 - t_x1) * (t_y2 - t_y1);

        const float b0x = v[CB + 0], b0y = v[CB + 1], b0w = v[CB + 2], b0h = v[CB + 3], b0c = v[CB + 4];
        const float b1x = v[CB + 5], b1y = v[CB + 6], b1w = v[CB + 7], b1h = v[CB + 8], b1c = v[CB + 9];

        float iou0, iou1;
        {
            const float cx = b0x * invS, cy = b0y * invS;
            const float x1 = cx - 0.5f * b0w, y1 = cy - 0.5f * b0h;
            const float x2 = cx + 0.5f * b0w, y2 = cy + 0.5f * b0h;
            const float iw = fmaxf(fminf(x2, t_x2) - fmaxf(x1, t_x1), 0.0f);
            const float ih = fmaxf(fminf(y2, t_y2) - fmaxf(y1, t_y1), 0.0f);
            const float inter = iw * ih;
            const float pa = (x2 - x1) * (y2 - y1);
            iou0 = inter / (pa + ta - inter);
        }
        {
            const float cx = b1x * invS, cy = b1y * invS;
            const float x1 = cx - 0.5f * b1w, y1 = cy - 0.5f * b1h;
            const float x2 = cx + 0.5f * b1w, y2 = cy + 0.5f * b1h;
            const float iw = fmaxf(fminf(x2, t_x2) - fmaxf(x1, t_x1), 0.0f);
            const float ih = fmaxf(fminf(y2, t_y2) - fmaxf(y1, t_y1), 0.0f);
            const float inter = iw * ih;
            const float pa = (x2 - x1) * (y2 - y1);
            iou1 = inter / (pa + ta - inter);
        }

        const bool sel1 = iou1 > iou0;   // jnp.argmax: first max wins -> strict >
        const float biou = fmaxf(iou0, iou1);
        const float rx = sel1 ? b1x : b0x;
        const float ry = sel1 ? b1y : b0y;
        const float rw = sel1 ? b1w : b0w;
        const float rh = sel1 ? b1h : b0h;
        const float rc = sel1 ? b1c : b0c;

        const float d0 = rx - tx, d1 = ry - ty;
        const float d2 = sqrtf(rw) - sqrtf(tw);
        const float d3 = sqrtf(rh) - sqrtf(th);
        reg += d0 * d0 + d1 * d1 + d2 * d2 + d3 * d3;

        const float dc = rc - biou;
        cont += dc * dc;

        noobj -= b0c * b0c + b1c * b1c;   // cancel sweep's count for this obj cell

        const float4* tc4 = reinterpret_cast<const float4*>(tcls + (size_t)cell * NCLS);
        float csum = 0.0f;
        #pragma unroll
        for (int j = 0; j < 5; ++j) {
            const float4 t4 = tc4[j];
            float d;
            d = v[CB + 10 + j * 4 + 0] - t4.x; csum += d * d;
            d = v[CB + 10 + j * 4 + 1] - t4.y; csum += d * d;
            d = v[CB + 10 + j * 4 + 2] - t4.z; csum += d * d;
            d = v[CB + 10 + j * 4 + 3] - t4.w; csum += d * d;
        }
        cls += csum;
    }
    // !m: nothing -- the sweep already counted this cell's conf^2.
}

__launch_bounds__(BLOCK)
__global__ void yolo_main_kernel(const float* __restrict__ pred,
                                 const float* __restrict__ tbox,
                                 const float* __restrict__ tcls,
                                 const void* __restrict__ mask,
                                 float* __restrict__ ws,
                                 int ncells, int nsub) {
    const int tid = threadIdx.x;
    const int role = blockIdx.x & 1;   // interleaved for CU co-residency
    const int sub = blockIdx.x >> 1;

    if (role == 0) {
        // ===== SWEEP: coalesced SUM_all conf^2 over flat pred =====
        // conf floats sit at row-offset 4 and 9 (row = 30 floats). For an
        // f4 at flat offset o (o%2==0), exactly one elem can be conf:
        //   p==4 -> .x (off 4), p==8 -> .y (off 9), p==2 -> .z (off 4),
        //   p==6 -> .w (off 9), where p = o % 30 (always even).
        const float4* p4 = reinterpret_cast<const float4*>(pred);
        const long long nf4 = ((long long)ncells * 30) >> 2;
        const long long stride = (long long)nsub * BLOCK;
        long long idx = (long long)sub * BLOCK + tid;
        int p = (int)((idx << 2) % 30);
        const int pstep = (int)((stride << 2) % 30);   // even
        float s = 0.0f;
        #pragma unroll 5
        for (; idx < nf4; idx += stride) {
            const float4 f = p4[idx];
            const float val = (p == 4) ? f.x
                            : (p == 8) ? f.y
                            : (p == 2) ? f.z
                            : (p == 6) ? f.w : 0.0f;
            s += val * val;
            p += pstep; if (p >= 30) p -= 30;
        }
        // scalar tail (ncells*30 % 4 == 2 possible only for odd ncells)
        if (sub == 0 && tid == 0) {
            for (long long o = nf4 << 2; o < (long long)ncells * 30; ++o) {
                const int r = (int)(o % 30);
                if (r == 4 || r == 9) { const float x = pred[o]; s += x * x; }
            }
        }
        #pragma unroll
        for (int off = 32; off > 0; off >>= 1) s += __shfl_down(s, off);
        __shared__ float sred1[4];
        if ((tid & 63) == 0) sred1[tid >> 6] = s;
        __syncthreads();
        if (tid == 0) {
            const float t = sred1[0] + sred1[1] + sred1[2] + sred1[3];
            atomicAdd(ws + (size_t)(blockIdx.x & (NSLOTS - 1)) * SLOT_STRIDE + 2, t);
        }
        return;
    }

    // ===== OBJ: gather rows only for obj cells =====
    // per-block mask-dtype sniff on first 4KB (fmt 0=int32, 1=u8, 2=f32)
    int my_bits = 0;
    if (ncells >= 4096) {
        const uint4 w4 = reinterpret_cast<const uint4*>(mask)[tid];
        const unsigned a = w4.x | w4.y | w4.z | w4.w;
        my_bits  = ((a & 0xFEFEFEFEu) != 0) ? 2 : 0;
        my_bits |= ((a & 0xFFFFFF00u) != 0) ? 1 : 0;
    } else if (tid == 0) {
        const unsigned char* mb = (const unsigned char*)mask;
        for (int i = 0; i < ncells; ++i) {
            if (mb[i] > 1) my_bits |= 2;
            if ((i & 3) != 0 && mb[i] != 0) my_bits |= 1;
        }
    }
    const int bits = __syncthreads_or(my_bits);
    const int fmt = (bits & 2) ? 2 : ((bits & 1) ? 1 : 0);

    const int g = sub * BLOCK + tid;
    const int c0 = g * CPT;

    float reg = 0.0f, cont = 0.0f, noobj = 0.0f, cls = 0.0f;

    if (c0 + CPT <= ncells) {
        bool m0, m1;
        if (fmt == 2) {
            const float2 mm = reinterpret_cast<const float2*>(mask)[g];
            m0 = mm.x != 0.0f; m1 = mm.y != 0.0f;
        } else if (fmt == 1) {
            const uchar2 mm = reinterpret_cast<const uchar2*>(mask)[g];
            m0 = mm.x != 0; m1 = mm.y != 0;
        } else {
            const int2 mm = reinterpret_cast<const int2*>(mask)[g];
            m0 = mm.x != 0; m1 = mm.y != 0;
        }

        float v[60];
        float4* v4 = reinterpret_cast<float4*>(v);
        const float4* prow = reinterpret_cast<const float4*>(pred) + (size_t)g * 15;
        // cell0 row = floats 0..29 = f4 0..7 ; cell1 row = floats 30..59 = f4 7..14
        if (m0) {
            #pragma unroll
            for (int j = 0; j < 8; ++j) v4[j] = prow[j];
        }
        if (m1) {
            #pragma unroll
            for (int j = 7; j < 15; ++j) v4[j] = prow[j];
        }

        cell_compute<0>(v, tbox, tcls, c0,     m0, reg, cont, noobj, cls);
        cell_compute<30>(v, tbox, tcls, c0 + 1, m1, reg, cont, noobj, cls);
    } else if (c0 < ncells) {
        // scalar tail (not hit when ncells % 512 == 0); same semantics
        for (int cell = c0; cell < ncells; ++cell) {
            bool m;
            if (fmt == 2)      m = ((const float*)mask)[cell] != 0.0f;
            else if (fmt == 1) m = ((const unsigned char*)mask)[cell] != 0;
            else               m = ((const int*)mask)[cell] != 0;
            float v[60];
            if (m) {
                #pragma unroll
                for (int f = 0; f < 30; ++f) v[f] = pred[(size_t)cell * 30 + f];
            }
            cell_compute<0>(v, tbox, tcls, cell, m, reg, cont, noobj, cls);
        }
    }

    // ---- wave64 + block reduce (4 counters) ----
    #pragma unroll
    for (int off = 32; off > 0; off >>= 1) {
        reg   += __shfl_down(reg, off);
        cont  += __shfl_down(cont, off);
        noobj += __shfl_down(noobj, off);
        cls   += __shfl_down(cls, off);
    }
    __shared__ float sred[4][4];
    const int wave = tid >> 6;
    if ((tid & 63) == 0) {
        sred[wave][0] = reg; sred[wave][1] = cont;
        sred[wave][2] = noobj; sred[wave][3] = cls;
    }
    __syncthreads();
    if (tid == 0) {
        float r = 0, c = 0, no = 0, cl = 0;
        #pragma unroll
        for (int w = 0; w < 4; ++w) {
            r += sred[w][0]; c += sred[w][1]; no += sred[w][2]; cl += sred[w][3];
        }
        float* slot = ws + (size_t)(blockIdx.x & (NSLOTS - 1)) * SLOT_STRIDE;
        atomicAdd(&slot[0], r);
        atomicAdd(&slot[1], c);
        atomicAdd(&slot[2], no);
        atomicAdd(&slot[3], cl);
    }
}

__global__ void yolo_finalize_kernel(const float* __restrict__ ws,
                                     float* __restrict__ out, float inv_n) {
    const int t = threadIdx.x;   // one wave: thread t owns slot t
    float reg   = ws[t * SLOT_STRIDE + 0];
    float cont  = ws[t * SLOT_STRIDE + 1];
    float noobj = ws[t * SLOT_STRIDE + 2];
    float cls   = ws[t * SLOT_STRIDE + 3];
    #pragma unroll
    for (int off = 32; off > 0; off >>= 1) {
        reg   += __shfl_down(reg, off);
        cont  += __shfl_down(cont, off);
        noobj += __shfl_down(noobj, off);
        cls   += __shfl_down(cls, off);
    }
    if (t == 0) {
        const float total = (5.0f * reg + 0.5f * noobj + cont + cls) * inv_n;
        out[0] = total;
        out[1] = reg;
        out[2] = cont;
        out[3] = noobj;
        out[4] = cls;
    }
}

extern "C" void kernel_launch(void* const* d_in, const int* in_sizes, int n_in,
                              void* d_out, int out_size, void* d_ws, size_t ws_size,
                              hipStream_t stream) {
    const float* pred = (const float*)d_in[0];
    const float* tbox = (const float*)d_in[1];
    const float* tcls = (const float*)d_in[2];
    const void*  mask = d_in[3];
    float* ws  = (float*)d_ws;
    float* out = (float*)d_out;

    const int ncells = in_sizes[3];                 // N * S * S
    const int n_img  = ncells / (GS * GS);          // N
    const float inv_n = 1.0f / (float)n_img;

    hipMemsetAsync(ws, 0, NSLOTS * SLOT_STRIDE * sizeof(float), stream);

    const int nblk_obj = (ncells + CPB - 1) / CPB;  // 1568
    const int grid = 2 * nblk_obj;                  // 3136, roles interleaved
    yolo_main_kernel<<<grid, BLOCK, 0, stream>>>(pred, tbox, tcls, mask, ws,
                                                 ncells, nblk_obj);

    yolo_finalize_kernel<<<1, 64, 0, stream>>>(ws, out, inv_n);
}